// Round 2
// baseline (399.951 us; speedup 1.0000x reference)
//
#include <hip/hip_runtime.h>
#include <stdint.h>

// Problem constants
#define NB   64          // batches
#define NS   64          // sensors
#define NT   2030        // time samples
#define NP   16384       // ROI*ROI pixels
#define DAS_ELEMS (NB * NP)          // 1,048,576
#define PIX_ELEMS ((size_t)NB * NS * NP)

// Window size for per-wave sinogram staging.
// A wave covers 256 consecutive ROI pixels = 2 full x-rows (rows are 128 px,
// wave base is a multiple of 256). Max pairwise pixel distance in that set:
// sqrt((127*0.2mm)^2 + (0.2mm)^2) = 25.4 mm -> max t spread = 25.4e-3/(C0*DT)
// = 678 samples. Window 1024 leaves 344 samples of margin (w0 may be pulled
// down by 1 for 8-byte alignment).
#define WIN 1024

typedef float v4f __attribute__((ext_vector_type(4)));

// ---------------------------------------------------------------------------
// Kernel 0: transpose geometry (pixel,s) -> (s,pixel), fusing clamp + valid.
// ---------------------------------------------------------------------------
__global__ __launch_bounds__(256) void prep_kernel(
    const int* __restrict__ t_idx, const float* __restrict__ w,
    int* __restrict__ tc, float* __restrict__ wv)
{
    __shared__ int   ti[64][65];
    __shared__ float wf[64][65];
    const int pbase = blockIdx.x * 64;

    #pragma unroll
    for (int k = 0; k < 16; ++k) {
        int o = k * 256 + threadIdx.x;     // 0..4095
        int r = o >> 6, s = o & 63;        // r = pixel-in-tile, s = sensor
        ti[r][s] = t_idx[pbase * 64 + o];
        wf[r][s] = w[pbase * 64 + o];
    }
    __syncthreads();

    #pragma unroll
    for (int k = 0; k < 16; ++k) {
        int o = k * 256 + threadIdx.x;
        int s = o >> 6, r = o & 63;
        int t = ti[r][s];
        bool valid = (t >= 0) & (t < NT);
        int tcl = min(max(t, 0), NT - 1);
        tc[s * NP + pbase + r] = tcl;
        wv[s * NP + pbase + r] = valid ? wf[r][s] : 0.0f;
    }
}

// ---------------------------------------------------------------------------
// Kernel 1 (fast path): per-wave windowed LDS staging, ZERO in-loop barriers.
//
// grid (16 pixel-tiles, 64 batches) x 256 threads; 4 px/thread.
// Each WAVE owns a private 2 x 1024-float LDS double buffer. Same-wave
// ds_write -> ds_read ordering is handled by compiler waitcnts; no
// __syncthreads in the sensor loop, so the 16 waves/CU stay fully
// independent and hide each other's LLC/HBM latency (round-1's block-wide
// barrier destroyed exactly this).
//
// Pipeline per iteration s:
//   - issue t/w loads for s+2 (distance-2 so the wave-min for s+1 never
//     waits on a fresh load)
//   - wave-min of t(s+1) -> window base w0n (even, <= NT-WIN); issue the
//     8 coalesced float2 window loads for s+1
//   - gather sensor s from LDS window (lane stride ~21 elems -> ~2-way
//     bank aliasing, free), multiply, nontemporal store, accumulate
//   - write s+1's window into the other buffer, rotate registers
// ---------------------------------------------------------------------------
__global__ __launch_bounds__(256) void main_lds_kernel(
    const float* __restrict__ sino,   // (B, S, T)
    const int*   __restrict__ tptr,   // (S, NP) pre-transposed, clamped
    const float* __restrict__ wptr,   // (S, NP) pre-transposed, masked
    float*       __restrict__ das,    // (B, NP) raw relu'd output
    float*       __restrict__ pix,    // (B, S, NP)
    unsigned*    __restrict__ bmax)   // per-batch max (float bits)
{
    __shared__ float sbuf[4][2][WIN];   // per-wave double buffers, 32 KB

    const int tid  = threadIdx.x;
    const int wid  = tid >> 6;
    const int lane = tid & 63;
    const int b = blockIdx.y;
    const int p = blockIdx.x * 1024 + tid * 4;
    const float* __restrict__ srow = sino + (size_t)b * (NS * NT);
    float* __restrict__ pixb = pix + (size_t)b * ((size_t)NS * NP) + p;
    float* const Lb = &sbuf[wid][0][0];

    // ---- prologue: t/w for s=0 and s=1, window+stage for s=0 ----
    int4   tq_cur = *(const int4*)  (tptr + 0 * NP + p);
    float4 wq_cur = *(const float4*)(wptr + 0 * NP + p);
    int4   tq_n1  = *(const int4*)  (tptr + 1 * NP + p);
    float4 wq_n1  = *(const float4*)(wptr + 1 * NP + p);

    int m0 = min(min(tq_cur.x, tq_cur.y), min(tq_cur.z, tq_cur.w));
    #pragma unroll
    for (int off = 32; off > 0; off >>= 1)
        m0 = min(m0, __shfl_xor(m0, off, 64));
    int w0c = min(m0, NT - WIN) & ~1;          // even => float2-aligned (NT even)
    {
        const float2* __restrict__ rr = (const float2*)(srow + w0c);
        float2* __restrict__ D = (float2*)Lb;  // buffer 0
        #pragma unroll
        for (int k = 0; k < 8; ++k)
            D[lane + 64 * k] = rr[lane + 64 * k];
    }
    int cur = 0;

    v4f acc = (v4f)(0.0f);

    for (int s = 0; s < NS; ++s) {
        // (a) issue t/w for s+2
        int4 tq_f; float4 wq_f;
        if (s + 2 < NS) {
            tq_f = *(const int4*)  (tptr + (s + 2) * NP + p);
            wq_f = *(const float4*)(wptr + (s + 2) * NP + p);
        }

        // (b) window base for s+1 from already-arrived t(s+1); issue loads
        int w0n = 0;
        float2 g0, g1, g2, g3, g4, g5, g6, g7;
        const bool haven = (s + 1 < NS);
        if (haven) {
            int mn = min(min(tq_n1.x, tq_n1.y), min(tq_n1.z, tq_n1.w));
            #pragma unroll
            for (int off = 32; off > 0; off >>= 1)
                mn = min(mn, __shfl_xor(mn, off, 64));
            w0n = min(mn, NT - WIN) & ~1;
            const float2* __restrict__ rr =
                (const float2*)(srow + (s + 1) * NT + w0n);
            g0 = rr[lane];        g1 = rr[lane + 64];
            g2 = rr[lane + 128];  g3 = rr[lane + 192];
            g4 = rr[lane + 256];  g5 = rr[lane + 320];
            g6 = rr[lane + 384];  g7 = rr[lane + 448];
        }

        // (c) gather sensor s from the wave's LDS window
        const float* __restrict__ Lc = Lb + cur * WIN;
        v4f v;
        v.x = Lc[tq_cur.x - w0c] * wq_cur.x;
        v.y = Lc[tq_cur.y - w0c] * wq_cur.y;
        v.z = Lc[tq_cur.z - w0c] * wq_cur.z;
        v.w = Lc[tq_cur.w - w0c] * wq_cur.w;
        __builtin_nontemporal_store(v, (v4f*)(pixb + (size_t)s * NP));
        acc += v;

        // (d) write s+1's window into the other buffer; rotate pipeline regs
        if (haven) {
            float2* __restrict__ D = (float2*)(Lb + (cur ^ 1) * WIN);
            D[lane]       = g0;  D[lane + 64]  = g1;
            D[lane + 128] = g2;  D[lane + 192] = g3;
            D[lane + 256] = g4;  D[lane + 320] = g5;
            D[lane + 384] = g6;  D[lane + 448] = g7;
            cur ^= 1;
            w0c = w0n;
            tq_cur = tq_n1; wq_cur = wq_n1;
            tq_n1  = tq_f;  wq_n1  = wq_f;
        }
    }

    // relu
    acc.x = fmaxf(acc.x, 0.f); acc.y = fmaxf(acc.y, 0.f);
    acc.z = fmaxf(acc.z, 0.f); acc.w = fmaxf(acc.w, 0.f);
    *(v4f*)(das + (size_t)b * NP + p) = acc;

    // block max -> per-batch atomic max
    float m = fmaxf(fmaxf(acc.x, acc.y), fmaxf(acc.z, acc.w));
    #pragma unroll
    for (int off = 32; off > 0; off >>= 1)
        m = fmaxf(m, __shfl_down(m, off, 64));
    __shared__ float wm[4];
    if (lane == 0) wm[wid] = m;
    __syncthreads();
    if (tid == 0) {
        m = fmaxf(fmaxf(wm[0], wm[1]), fmaxf(wm[2], wm[3]));
        atomicMax(&bmax[b], __float_as_uint(m));   // all values >= 0: uint order == float order
    }
}

// ---------------------------------------------------------------------------
// Kernel 1 (fallback, ws too small): original non-transposed path.
// ---------------------------------------------------------------------------
__global__ __launch_bounds__(256) void main_fallback_kernel(
    const float* __restrict__ sino,
    const int*   __restrict__ tptr,
    const float* __restrict__ wptr,
    float*       __restrict__ das,
    float*       __restrict__ pix,
    unsigned*    __restrict__ bmax)
{
    const int b = blockIdx.y;
    const int p = blockIdx.x * 1024 + threadIdx.x * 4;
    const float* __restrict__ srow = sino + (size_t)b * (NS * NT);
    float* __restrict__ pixb = pix + (size_t)b * ((size_t)NS * NP) + p;

    v4f acc = (v4f)(0.0f);

    for (int s = 0; s < NS; ++s) {
        int t0 = tptr[(p + 0) * NS + s];
        int t1 = tptr[(p + 1) * NS + s];
        int t2 = tptr[(p + 2) * NS + s];
        int t3 = tptr[(p + 3) * NS + s];
        float wx = ((t0 >= 0) & (t0 < NT)) ? wptr[(p + 0) * NS + s] : 0.f;
        float wy = ((t1 >= 0) & (t1 < NT)) ? wptr[(p + 1) * NS + s] : 0.f;
        float wz = ((t2 >= 0) & (t2 < NT)) ? wptr[(p + 2) * NS + s] : 0.f;
        float ww = ((t3 >= 0) & (t3 < NT)) ? wptr[(p + 3) * NS + s] : 0.f;
        int4 t;
        t.x = min(max(t0, 0), NT - 1);
        t.y = min(max(t1, 0), NT - 1);
        t.z = min(max(t2, 0), NT - 1);
        t.w = min(max(t3, 0), NT - 1);
        const float* __restrict__ sr = srow + s * NT;
        v4f v;
        v.x = sr[t.x] * wx;
        v.y = sr[t.y] * wy;
        v.z = sr[t.z] * wz;
        v.w = sr[t.w] * ww;
        __builtin_nontemporal_store(v, (v4f*)(pixb + (size_t)s * NP));
        acc += v;
    }

    acc.x = fmaxf(acc.x, 0.f); acc.y = fmaxf(acc.y, 0.f);
    acc.z = fmaxf(acc.z, 0.f); acc.w = fmaxf(acc.w, 0.f);
    *(v4f*)(das + (size_t)b * NP + p) = acc;

    float m = fmaxf(fmaxf(acc.x, acc.y), fmaxf(acc.z, acc.w));
    #pragma unroll
    for (int off = 32; off > 0; off >>= 1)
        m = fmaxf(m, __shfl_down(m, off, 64));
    __shared__ float wm[4];
    if ((threadIdx.x & 63) == 0) wm[threadIdx.x >> 6] = m;
    __syncthreads();
    if (threadIdx.x == 0) {
        m = fmaxf(fmaxf(wm[0], wm[1]), fmaxf(wm[2], wm[3]));
        atomicMax(&bmax[b], __float_as_uint(m));
    }
}

// ---------------------------------------------------------------------------
// Kernel 2: normalize das in place. 1M elems / 4 per thread.
// ---------------------------------------------------------------------------
__global__ __launch_bounds__(256) void norm_kernel(
    float* __restrict__ das, const unsigned* __restrict__ bmax)
{
    int idx = (blockIdx.x * 256 + threadIdx.x) * 4;
    int b = idx >> 14;                   // NP = 16384 pixels per batch
    float m = __uint_as_float(bmax[b]);
    m = (m > 1e-8f) ? m : 1.0f;
    v4f v = *(v4f*)(das + idx);
    v.x = v.x / m; v.y = v.y / m; v.z = v.z / m; v.w = v.w / m;
    *(v4f*)(das + idx) = v;
}

extern "C" void kernel_launch(void* const* d_in, const int* in_sizes, int n_in,
                              void* d_out, int out_size, void* d_ws, size_t ws_size,
                              hipStream_t stream)
{
    const float* sino  = (const float*)d_in[0];   // (64,1,64,2030) f32
    const float* w     = (const float*)d_in[1];   // (128,128,64)   f32
    const int*   t_idx = (const int*)  d_in[2];   // (128,128,64)   i32
    // d_in[3] (valid_mask) intentionally unused: valid == (0 <= t_idx < NT)

    float* das = (float*)d_out;                   // first 1,048,576 floats
    float* pix = (float*)d_out + DAS_ELEMS;       // next 67,108,864 floats

    char* ws = (char*)d_ws;
    const size_t need = (size_t)(8u << 20) + 256;
    const bool big = ws_size >= need;

    unsigned* bmax;
    int* tc = nullptr; float* wv = nullptr;
    if (big) {
        tc   = (int*)ws;                          // 4 MB
        wv   = (float*)(ws + (4u << 20));         // 4 MB
        bmax = (unsigned*)(ws + (8u << 20));      // 256 B
    } else {
        bmax = (unsigned*)ws;                     // need only 256 B
    }

    (void)hipMemsetAsync(bmax, 0, NB * sizeof(unsigned), stream);

    if (big) {
        prep_kernel<<<256, 256, 0, stream>>>(t_idx, w, tc, wv);
        main_lds_kernel<<<dim3(16, NB), 256, 0, stream>>>(sino, tc, wv, das, pix, bmax);
    } else {
        main_fallback_kernel<<<dim3(16, NB), 256, 0, stream>>>(sino, t_idx, w, das, pix, bmax);
    }
    norm_kernel<<<DAS_ELEMS / 1024, 256, 0, stream>>>(das, bmax);
}

// Round 3
// 367.228 us; speedup vs baseline: 1.0891x; 1.0891x over previous
//
#include <hip/hip_runtime.h>
#include <stdint.h>

// Problem constants
#define NB   64          // batches
#define NS   64          // sensors
#define NT   2030        // time samples
#define NP   16384       // ROI*ROI pixels
#define DAS_ELEMS (NB * NP)          // 1,048,576

typedef float v4f __attribute__((ext_vector_type(4)));

// ---------------------------------------------------------------------------
// Kernel 0: transpose geometry (pixel,s) -> (s,pixel), fusing clamp + valid.
//   tc[s*NP + p] = (u16)clamp(t_idx[p*NS + s], 0, NT-1)   (NT < 65536)
//   wv[s*NP + p] = (0 <= t < NT) ? weights[p*NS + s] : 0
// u16 t cuts the per-batch geometry re-read traffic by 1/4.
// ---------------------------------------------------------------------------
__global__ __launch_bounds__(256) void prep_kernel(
    const int* __restrict__ t_idx, const float* __restrict__ w,
    unsigned short* __restrict__ tc, float* __restrict__ wv)
{
    __shared__ int   ti[64][65];
    __shared__ float wf[64][65];
    const int pbase = blockIdx.x * 64;

    #pragma unroll
    for (int k = 0; k < 16; ++k) {
        int o = k * 256 + threadIdx.x;     // 0..4095
        int r = o >> 6, s = o & 63;        // r = pixel-in-tile, s = sensor
        ti[r][s] = t_idx[pbase * 64 + o];
        wf[r][s] = w[pbase * 64 + o];
    }
    __syncthreads();

    #pragma unroll
    for (int k = 0; k < 16; ++k) {
        int o = k * 256 + threadIdx.x;
        int s = o >> 6, r = o & 63;
        int t = ti[r][s];
        bool valid = (t >= 0) & (t < NT);
        int tcl = min(max(t, 0), NT - 1);
        tc[s * NP + pbase + r] = (unsigned short)tcl;
        wv[s * NP + pbase + r] = valid ? wf[r][s] : 0.0f;
    }
}

// ---------------------------------------------------------------------------
// Kernel 1 (fast path): VMEM-gather DAS, strided pixel mapping + batch pair.
//
// grid (32 pixel-tiles, 32 batch-pairs) x 256 threads = 1024 blocks (4/CU,
// 16 waves/CU). Each thread owns pixels {p, p+256} (p = tile*512 + tid) for
// batches {2*bg, 2*bg+1}.
//
// Why strided: with 4 CONSECUTIVE px/thread (old), lane-to-lane delta-t was
// ~4*5.3 samples = 84 B -> each gather instr fragmented into ~64 L1 line
// transactions. With stride-256 groups, adjacent lanes' t differ by ~5.3
// samples = 21 B -> ~3 lanes share each 64 B line -> ~22 transactions per
// gather instr (~3x less L1 pressure, the round-0 bottleneck).
// Batch pairing halves the per-batch geometry re-read (t/w registers reused
// for two sinograms); u16 t quarters it again.
// No LDS, no in-loop barriers (rounds 1-2 proved both are net losses here).
// ---------------------------------------------------------------------------
__global__ __launch_bounds__(256) void main_strided_kernel(
    const float* __restrict__ sino,          // (B, S, T)
    const unsigned short* __restrict__ tptr, // (S, NP) clamped u16
    const float* __restrict__ wptr,          // (S, NP) masked
    float*       __restrict__ das,           // (B, NP) raw relu'd
    float*       __restrict__ pix,           // (B, S, NP)
    unsigned*    __restrict__ bmax)          // per-batch max (float bits)
{
    const int tid = threadIdx.x;
    const int p   = blockIdx.x * 512 + tid;  // group-0 pixel
    const int b0  = blockIdx.y * 2, b1 = b0 + 1;
    const float* __restrict__ sr0 = sino + (size_t)b0 * (NS * NT);
    const float* __restrict__ sr1 = sino + (size_t)b1 * (NS * NT);
    float* __restrict__ pix0 = pix + ((size_t)b0 * NS) * NP + p;
    float* __restrict__ pix1 = pix + ((size_t)b1 * NS) * NP + p;

    float a00 = 0.f, a01 = 0.f, a10 = 0.f, a11 = 0.f;

    // prefetch t/w for s = 0
    int t0, t1; float w0, w1;
    {
        const unsigned short* tp = tptr + p;
        const float*          wp = wptr + p;
        t0 = tp[0]; t1 = tp[256];
        w0 = wp[0]; w1 = wp[256];
    }

    for (int s = 0; s < NS; ++s) {
        // distance-1 register prefetch of next sensor's t/w (L2/L3 latency
        // hides under this iteration's gathers/stores)
        int nt0 = 0, nt1 = 0; float nw0 = 0.f, nw1 = 0.f;
        if (s + 1 < NS) {
            const unsigned short* tp = tptr + (s + 1) * NP + p;
            const float*          wp = wptr + (s + 1) * NP + p;
            nt0 = tp[0]; nt1 = tp[256];
            nw0 = wp[0]; nw1 = wp[256];
        }

        const float* __restrict__ r0 = sr0 + s * NT;
        const float* __restrict__ r1 = sr1 + s * NT;
        float v00 = r0[t0] * w0;
        float v01 = r0[t1] * w1;
        float v10 = r1[t0] * w0;
        float v11 = r1[t1] * w1;

        float* q0 = pix0 + (size_t)s * NP;
        float* q1 = pix1 + (size_t)s * NP;
        __builtin_nontemporal_store(v00, q0);
        __builtin_nontemporal_store(v01, q0 + 256);
        __builtin_nontemporal_store(v10, q1);
        __builtin_nontemporal_store(v11, q1 + 256);

        a00 += v00; a01 += v01; a10 += v10; a11 += v11;

        t0 = nt0; t1 = nt1; w0 = nw0; w1 = nw1;
    }

    // relu
    a00 = fmaxf(a00, 0.f); a01 = fmaxf(a01, 0.f);
    a10 = fmaxf(a10, 0.f); a11 = fmaxf(a11, 0.f);
    das[(size_t)b0 * NP + p]       = a00;
    das[(size_t)b0 * NP + p + 256] = a01;
    das[(size_t)b1 * NP + p]       = a10;
    das[(size_t)b1 * NP + p + 256] = a11;

    // per-batch block max -> atomic max (two batches, two reductions)
    float m0 = fmaxf(a00, a01);
    float m1 = fmaxf(a10, a11);
    #pragma unroll
    for (int off = 32; off > 0; off >>= 1) {
        m0 = fmaxf(m0, __shfl_down(m0, off, 64));
        m1 = fmaxf(m1, __shfl_down(m1, off, 64));
    }
    __shared__ float wm0[4], wm1[4];
    const int wid = tid >> 6, lane = tid & 63;
    if (lane == 0) { wm0[wid] = m0; wm1[wid] = m1; }
    __syncthreads();
    if (tid == 0) {
        m0 = fmaxf(fmaxf(wm0[0], wm0[1]), fmaxf(wm0[2], wm0[3]));
        m1 = fmaxf(fmaxf(wm1[0], wm1[1]), fmaxf(wm1[2], wm1[3]));
        atomicMax(&bmax[b0], __float_as_uint(m0));  // vals >= 0: uint order == float order
        atomicMax(&bmax[b1], __float_as_uint(m1));
    }
}

// ---------------------------------------------------------------------------
// Kernel 1 (fallback, ws too small): original non-transposed path.
// ---------------------------------------------------------------------------
__global__ __launch_bounds__(256) void main_fallback_kernel(
    const float* __restrict__ sino,
    const int*   __restrict__ tptr,
    const float* __restrict__ wptr,
    float*       __restrict__ das,
    float*       __restrict__ pix,
    unsigned*    __restrict__ bmax)
{
    const int b = blockIdx.y;
    const int p = blockIdx.x * 1024 + threadIdx.x * 4;
    const float* __restrict__ srow = sino + (size_t)b * (NS * NT);
    float* __restrict__ pixb = pix + (size_t)b * ((size_t)NS * NP) + p;

    v4f acc = (v4f)(0.0f);

    for (int s = 0; s < NS; ++s) {
        int t0 = tptr[(p + 0) * NS + s];
        int t1 = tptr[(p + 1) * NS + s];
        int t2 = tptr[(p + 2) * NS + s];
        int t3 = tptr[(p + 3) * NS + s];
        float wx = ((t0 >= 0) & (t0 < NT)) ? wptr[(p + 0) * NS + s] : 0.f;
        float wy = ((t1 >= 0) & (t1 < NT)) ? wptr[(p + 1) * NS + s] : 0.f;
        float wz = ((t2 >= 0) & (t2 < NT)) ? wptr[(p + 2) * NS + s] : 0.f;
        float ww = ((t3 >= 0) & (t3 < NT)) ? wptr[(p + 3) * NS + s] : 0.f;
        int4 t;
        t.x = min(max(t0, 0), NT - 1);
        t.y = min(max(t1, 0), NT - 1);
        t.z = min(max(t2, 0), NT - 1);
        t.w = min(max(t3, 0), NT - 1);
        const float* __restrict__ sr = srow + s * NT;
        v4f v;
        v.x = sr[t.x] * wx;
        v.y = sr[t.y] * wy;
        v.z = sr[t.z] * wz;
        v.w = sr[t.w] * ww;
        __builtin_nontemporal_store(v, (v4f*)(pixb + (size_t)s * NP));
        acc += v;
    }

    acc.x = fmaxf(acc.x, 0.f); acc.y = fmaxf(acc.y, 0.f);
    acc.z = fmaxf(acc.z, 0.f); acc.w = fmaxf(acc.w, 0.f);
    *(v4f*)(das + (size_t)b * NP + p) = acc;

    float m = fmaxf(fmaxf(acc.x, acc.y), fmaxf(acc.z, acc.w));
    #pragma unroll
    for (int off = 32; off > 0; off >>= 1)
        m = fmaxf(m, __shfl_down(m, off, 64));
    __shared__ float wm[4];
    if ((threadIdx.x & 63) == 0) wm[threadIdx.x >> 6] = m;
    __syncthreads();
    if (threadIdx.x == 0) {
        m = fmaxf(fmaxf(wm[0], wm[1]), fmaxf(wm[2], wm[3]));
        atomicMax(&bmax[b], __float_as_uint(m));
    }
}

// ---------------------------------------------------------------------------
// Kernel 2: normalize das in place. 1M elems / 4 per thread.
// ---------------------------------------------------------------------------
__global__ __launch_bounds__(256) void norm_kernel(
    float* __restrict__ das, const unsigned* __restrict__ bmax)
{
    int idx = (blockIdx.x * 256 + threadIdx.x) * 4;
    int b = idx >> 14;                   // NP = 16384 pixels per batch
    float m = __uint_as_float(bmax[b]);
    m = (m > 1e-8f) ? m : 1.0f;
    v4f v = *(v4f*)(das + idx);
    v.x = v.x / m; v.y = v.y / m; v.z = v.z / m; v.w = v.w / m;
    *(v4f*)(das + idx) = v;
}

extern "C" void kernel_launch(void* const* d_in, const int* in_sizes, int n_in,
                              void* d_out, int out_size, void* d_ws, size_t ws_size,
                              hipStream_t stream)
{
    const float* sino  = (const float*)d_in[0];   // (64,1,64,2030) f32
    const float* w     = (const float*)d_in[1];   // (128,128,64)   f32
    const int*   t_idx = (const int*)  d_in[2];   // (128,128,64)   i32
    // d_in[3] (valid_mask) intentionally unused: valid == (0 <= t_idx < NT)

    float* das = (float*)d_out;                   // first 1,048,576 floats
    float* pix = (float*)d_out + DAS_ELEMS;       // next 67,108,864 floats

    char* ws = (char*)d_ws;
    // layout: wv f32 (4 MB) | tc u16 (2 MB) | bmax (256 B)
    const size_t need = (size_t)(6u << 20) + 256;
    const bool big = ws_size >= need;

    unsigned* bmax;
    float* wv = nullptr; unsigned short* tc = nullptr;
    if (big) {
        wv   = (float*)ws;                            // 4 MB
        tc   = (unsigned short*)(ws + (4u << 20));    // 2 MB
        bmax = (unsigned*)(ws + (6u << 20));          // 256 B
    } else {
        bmax = (unsigned*)ws;                         // need only 256 B
    }

    (void)hipMemsetAsync(bmax, 0, NB * sizeof(unsigned), stream);

    if (big) {
        prep_kernel<<<256, 256, 0, stream>>>(t_idx, w, tc, wv);
        main_strided_kernel<<<dim3(32, 32), 256, 0, stream>>>(sino, tc, wv, das, pix, bmax);
    } else {
        main_fallback_kernel<<<dim3(16, NB), 256, 0, stream>>>(sino, t_idx, w, das, pix, bmax);
    }
    norm_kernel<<<DAS_ELEMS / 1024, 256, 0, stream>>>(das, bmax);
}